// Round 13
// baseline (200.846 us; speedup 1.0000x reference)
//
#include <hip/hip_runtime.h>
#include <stdint.h>

// Problem constants: B=32, N=1024, C=64, G=64
// ws: k_ws fp16[32768*64] (4MB) | vt_ws fp16[32*64*1024] (4MB) | flags[32] @ 8MB,
//     one 128-B line per batch.
//
// R13: single fused kernel with PER-BATCH producer/consumer sync (fixes R10's
// global RMW-spin barrier: 110us -> expected ~1-2us). Each block produces its
// own 64-row K/V tile once (prologue), arrives at its batch counter
// (atomicAdd), then polls with device-scope atomic LOADS (no RMW) until all
// 16 siblings arrived. Attn loop reads K/V from ws (R6 structure,
// 1 barrier/tile, 16 MFMA/tile/wave). Co-residency guaranteed:
// launch_bounds(256,2) + 64KB LDS -> 2 blocks/CU x 256 CU = 512.

typedef __attribute__((ext_vector_type(4))) float    floatx4;
typedef __attribute__((ext_vector_type(8))) _Float16 halfx8;

static __device__ __forceinline__ unsigned short f2h(float f) {
    union { _Float16 h; unsigned short u; } v; v.h = (_Float16)f;
    return v.u;
}
static __device__ __forceinline__ float h2f(unsigned short u) {
    union { unsigned short u; _Float16 h; } v; v.u = u;
    return (float)v.h;
}

__global__ __launch_bounds__(256, 2) void fused_attn_kernel(
    const float* __restrict__ x,
    const float* __restrict__ Wq, const float* __restrict__ bq,
    const float* __restrict__ Wk, const float* __restrict__ bk,
    const float* __restrict__ Wv, const float* __restrict__ bv,
    const int* __restrict__ valid_len,
    unsigned short* __restrict__ k_ws, unsigned short* __restrict__ vt_ws,
    unsigned int* flags, float* __restrict__ out)
{
    // Phase A: [0,4096)=xs_hi (later q_lds, SURVIVES into B), [4096,8192)=xs_lo
    // (later k_lds), [8192,32768)=6 W^T planes (vtmp aliases post-MFMA).
    // Phase B: [0,4096)=qs, [4096..12288)=kbuf[2], [12288..20480)=vbuf[2],
    // [20480,24576)=ps.
    __shared__ __align__(16) unsigned short smem[8 * 4096];      // 64 KB
    float* vtmp = (float*)&smem[2 * 4096];

    const int XS_HI = 0, XS_LO = 4096;
    #define WT_OFF(i) (2 * 4096 + (i) * 4096)

    const int tid  = threadIdx.x;
    const int blk  = blockIdx.x;          // 0..511
    const int row0 = blk * 64;            // b*1024 + n0
    const int b    = blk >> 4;
    const int lane = tid & 63;
    const int w    = tid >> 6;
    const int l15  = lane & 15;
    const int quad = lane >> 4;

    // ======================= Phase A: QKV projection =======================
#pragma unroll
    for (int i = 0; i < 2; ++i) {
        int id = i * 256 + tid;
        int r = id >> 3, c8 = id & 7;
        const float4* gp = (const float4*)(x + (row0 + r) * 64 + c8 * 8);
        float4 f0 = gp[0], f1 = gp[1];
        float fv[8] = { f0.x, f0.y, f0.z, f0.w, f1.x, f1.y, f1.z, f1.w };
        __align__(16) unsigned short thi[8], tlo[8];
#pragma unroll
        for (int j = 0; j < 8; ++j) {
            unsigned short hi = f2h(fv[j]);
            thi[j] = hi;
            tlo[j] = f2h(fv[j] - h2f(hi));
        }
        int idx = r * 64 + ((c8 ^ (r & 7)) * 8);
        *(uint4*)&smem[XS_HI + idx] = *(uint4*)thi;
        *(uint4*)&smem[XS_LO + idx] = *(uint4*)tlo;
    }
    {
        const float* Ws[3] = { Wq, Wk, Wv };
        int g = tid & 63, ci = tid >> 6;
#pragma unroll
        for (int wi = 0; wi < 3; ++wi) {
#pragma unroll
            for (int j = 0; j < 16; ++j) {
                int c = ci * 16 + j;
                float f = Ws[wi][c * 64 + g];
                unsigned short hi = f2h(f);
                unsigned short lo = f2h(f - h2f(hi));
                int idx = g * 64 + (((c >> 3) ^ (g & 7)) * 8) + (c & 7);
                smem[WT_OFF(wi * 2 + 0) + idx] = hi;
                smem[WT_OFF(wi * 2 + 1) + idx] = lo;
            }
        }
    }
    __syncthreads();

    const int arow = w * 16 + l15;
    const int aidx0 = arow * 64 + (((0 + quad) ^ (arow & 7)) * 8);
    const int aidx1 = arow * 64 + (((4 + quad) ^ (arow & 7)) * 8);
    halfx8 a_hi0 = *(const halfx8*)&smem[XS_HI + aidx0];
    halfx8 a_hi1 = *(const halfx8*)&smem[XS_HI + aidx1];
    halfx8 a_lo0 = *(const halfx8*)&smem[XS_LO + aidx0];
    halfx8 a_lo1 = *(const halfx8*)&smem[XS_LO + aidx1];

    __syncthreads();   // frags in regs -> xs region reusable as q_lds/k_lds

    unsigned short* q_lds = &smem[0];      // q stays here through phase B
    unsigned short* k_lds = &smem[4096];

    const float* biases[3] = { bq, bk, bv };
    floatx4 vacc[4];
#pragma unroll
    for (int wi = 0; wi < 3; ++wi) {
#pragma unroll
        for (int gs = 0; gs < 4; ++gs) {
            int g0 = gs * 16;
            float bias = biases[wi][g0 + l15];
            floatx4 acc = { bias, bias, bias, bias };
            int brow = g0 + l15;
            int bidx0 = brow * 64 + (((0 + quad) ^ (brow & 7)) * 8);
            int bidx1 = brow * 64 + (((4 + quad) ^ (brow & 7)) * 8);
            halfx8 b_hi0 = *(const halfx8*)&smem[WT_OFF(wi * 2 + 0) + bidx0];
            halfx8 b_hi1 = *(const halfx8*)&smem[WT_OFF(wi * 2 + 0) + bidx1];
            halfx8 b_lo0 = *(const halfx8*)&smem[WT_OFF(wi * 2 + 1) + bidx0];
            halfx8 b_lo1 = *(const halfx8*)&smem[WT_OFF(wi * 2 + 1) + bidx1];
            acc = __builtin_amdgcn_mfma_f32_16x16x32_f16(a_hi0, b_hi0, acc, 0, 0, 0);
            acc = __builtin_amdgcn_mfma_f32_16x16x32_f16(a_hi1, b_hi1, acc, 0, 0, 0);
            acc = __builtin_amdgcn_mfma_f32_16x16x32_f16(a_hi0, b_lo0, acc, 0, 0, 0);
            acc = __builtin_amdgcn_mfma_f32_16x16x32_f16(a_hi1, b_lo1, acc, 0, 0, 0);
            acc = __builtin_amdgcn_mfma_f32_16x16x32_f16(a_lo0, b_hi0, acc, 0, 0, 0);
            acc = __builtin_amdgcn_mfma_f32_16x16x32_f16(a_lo1, b_hi1, acc, 0, 0, 0);
            if (wi < 2) {
                unsigned short* dst = (wi == 0) ? q_lds : k_lds;
                int c8 = gs * 2 + (l15 >> 3);
#pragma unroll
                for (int r = 0; r < 4; ++r) {
                    int row = w * 16 + quad * 4 + r;   // wave-private rows
                    dst[row * 64 + ((c8 ^ (row & 7)) * 8) + (l15 & 7)] = f2h(acc[r]);
                }
            } else {
                vacc[gs] = acc;
            }
        }
    }

    __syncthreads();   // MFMAs done (wT free for vtmp), q/k LDS complete

    // --- coalesced k store (q stays in LDS) ---
#pragma unroll
    for (int i = 0; i < 2; ++i) {
        int id = i * 256 + tid;
        int r = id >> 3, c8 = id & 7;
        int sidx = r * 64 + ((c8 ^ (r & 7)) * 8);
        *(uint4*)(k_ws + (row0 + r) * 64 + c8 * 8) = *(const uint4*)&k_lds[sidx];
    }
    // --- v transpose through fp32 LDS -> vt_ws [g][n] ---
#pragma unroll
    for (int gs = 0; gs < 4; ++gs) {
#pragma unroll
        for (int r = 0; r < 4; ++r) {
            int nl = w * 16 + quad * 4 + r;
            vtmp[(gs * 16 + l15) * 65 + nl] = vacc[gs][r];
        }
    }
    __syncthreads();
    {
        int n0 = (blk & 15) * 64;
        int g = tid >> 2, c4 = tid & 3;
        __align__(16) unsigned short tmp[16];
#pragma unroll
        for (int j = 0; j < 16; ++j) tmp[j] = f2h(vtmp[g * 65 + c4 * 16 + j]);
        unsigned short* dst = vt_ws + (b * 64 + g) * 1024 + n0 + c4 * 16;
        *(uint4*)(dst)     = ((uint4*)tmp)[0];
        *(uint4*)(dst + 8) = ((uint4*)tmp)[1];
    }
    #undef WT_OFF

    // ============ per-batch rendezvous (16 producer blocks) ============
    unsigned int* flag_b = flags + b * 32;     // 128-B line per batch
    __threadfence();                           // release k_ws/vt_ws stores
    __syncthreads();                           // all waves' stores issued+fenced
    if (tid == 0) {
        atomicAdd(flag_b, 1u);                 // arrive (one RMW per block)
        while (__hip_atomic_load(flag_b, __ATOMIC_ACQUIRE,
                                 __HIP_MEMORY_SCOPE_AGENT) < 16u)
            __builtin_amdgcn_s_sleep(8);       // read-only poll, <=15 pollers/line
    }
    __syncthreads();
    __threadfence();                           // acquire for K/V reads

    // ======================= Phase B: flash attention ======================
    unsigned short* qs    = &smem[0];          // preserved q tile
    unsigned short* kbufA = &smem[4096];
    unsigned short* kbufB = &smem[8192];
    unsigned short* vbufA = &smem[12288];
    unsigned short* vbufB = &smem[16384];
    unsigned short* ps    = &smem[20480];

    const int r_a  = tid >> 3,          c8_a = tid & 7;
    const int r_b  = (256 + tid) >> 3,  c8_b = tid & 7;
    const int lidx_a = r_a * 64 + ((c8_a ^ (r_a & 7)) * 8);
    const int lidx_b = r_b * 64 + ((c8_b ^ (r_b & 7)) * 8);

    const int vl    = valid_len[b];
    const int nt    = (vl == 0) ? 16 : ((vl + 63) >> 6);
    const int fullt = vl >> 6;

    const unsigned short* kbase = k_ws + (size_t)b * 1024 * 64;
    const unsigned short* vbase = vt_ws + (size_t)b * 64 * 1024;

    uint4 kr0 = *(const uint4*)(kbase + r_a * 64 + c8_a * 8);
    uint4 kr1 = *(const uint4*)(kbase + r_b * 64 + c8_b * 8);
    uint4 vr0 = *(const uint4*)(vbase + r_a * 1024 + c8_a * 8);
    uint4 vr1 = *(const uint4*)(vbase + r_b * 1024 + c8_b * 8);
    *(uint4*)&kbufA[lidx_a] = kr0;
    *(uint4*)&kbufA[lidx_b] = kr1;
    *(uint4*)&vbufA[lidx_a] = vr0;
    *(uint4*)&vbufA[lidx_b] = vr1;

    __syncthreads();

    const int qidx0 = aidx0, qidx1 = aidx1;
    halfx8 aq0 = *(const halfx8*)&qs[qidx0];
    halfx8 aq1 = *(const halfx8*)&qs[qidx1];

    float m_r[4]    = { -INFINITY, -INFINITY, -INFINITY, -INFINITY };
    float l_lane[4] = { 0.f, 0.f, 0.f, 0.f };
    floatx4 o[4] = { {0,0,0,0}, {0,0,0,0}, {0,0,0,0}, {0,0,0,0} };

    for (int t = 0; t < nt; ++t) {
        bool pre = (t + 1) < nt;
        if (pre) {
            const unsigned short* kp = kbase + (t + 1) * 64 * 64;
            const unsigned short* vp = vbase + (t + 1) * 64;
            kr0 = *(const uint4*)(kp + r_a * 64 + c8_a * 8);
            kr1 = *(const uint4*)(kp + r_b * 64 + c8_b * 8);
            vr0 = *(const uint4*)(vp + r_a * 1024 + c8_a * 8);
            vr1 = *(const uint4*)(vp + r_b * 1024 + c8_b * 8);
        }
        if (t > 0) __syncthreads();
        if (pre) {
            unsigned short* kn = ((t + 1) & 1) ? kbufB : kbufA;
            unsigned short* vn = ((t + 1) & 1) ? vbufB : vbufA;
            *(uint4*)&kn[lidx_a] = kr0;
            *(uint4*)&kn[lidx_b] = kr1;
            *(uint4*)&vn[lidx_a] = vr0;
            *(uint4*)&vn[lidx_b] = vr1;
        }
        const unsigned short* ksb = (t & 1) ? kbufB : kbufA;
        const unsigned short* vsb = (t & 1) ? vbufB : vbufA;

        floatx4 s[4];
#pragma unroll
        for (int sub = 0; sub < 4; ++sub) {
            int krow = sub * 16 + l15;
            halfx8 bk0 = *(const halfx8*)&ksb[krow * 64 + (((0 + quad) ^ (krow & 7)) * 8)];
            halfx8 bk1 = *(const halfx8*)&ksb[krow * 64 + (((4 + quad) ^ (krow & 7)) * 8)];
            floatx4 acc = { 0, 0, 0, 0 };
            acc = __builtin_amdgcn_mfma_f32_16x16x32_f16(aq0, bk0, acc, 0, 0, 0);
            acc = __builtin_amdgcn_mfma_f32_16x16x32_f16(aq1, bk1, acc, 0, 0, 0);
            s[sub] = acc;
        }
        if (t >= fullt) {
#pragma unroll
            for (int sub = 0; sub < 4; ++sub) {
                int key = t * 64 + sub * 16 + l15;
                if (key >= vl) { s[sub][0] = -1e6f; s[sub][1] = -1e6f; s[sub][2] = -1e6f; s[sub][3] = -1e6f; }
            }
        }

        float p[4][4];
        float alpha[4];
#pragma unroll
        for (int r = 0; r < 4; ++r) {
            float mx = fmaxf(fmaxf(s[0][r], s[1][r]), fmaxf(s[2][r], s[3][r]));
#pragma unroll
            for (int off = 1; off < 16; off <<= 1)
                mx = fmaxf(mx, __shfl_xor(mx, off, 64));
            float mnew = fmaxf(m_r[r], mx);
            alpha[r] = __expf(m_r[r] - mnew);
            float psum = 0.f;
#pragma unroll
            for (int sub = 0; sub < 4; ++sub) {
                float pv = __expf(s[sub][r] - mnew);
                p[sub][r] = pv;
                psum += pv;
            }
            l_lane[r] = l_lane[r] * alpha[r] + psum;
            m_r[r] = mnew;
        }
#pragma unroll
        for (int gs = 0; gs < 4; ++gs) {
            o[gs][0] *= alpha[0]; o[gs][1] *= alpha[1];
            o[gs][2] *= alpha[2]; o[gs][3] *= alpha[3];
        }

        unsigned short* psw = &ps[w * 1024];
#pragma unroll
        for (int sub = 0; sub < 4; ++sub) {
            int c8 = sub * 2 + (l15 >> 3);
#pragma unroll
            for (int r = 0; r < 4; ++r) {
                int row = quad * 4 + r;
                psw[row * 64 + ((c8 ^ (row & 7)) * 8) + (l15 & 7)] = f2h(p[sub][r]);
            }
        }
        halfx8 ap0 = *(const halfx8*)&psw[l15 * 64 + (((0 + quad) ^ (l15 & 7)) * 8)];
        halfx8 ap1 = *(const halfx8*)&psw[l15 * 64 + (((4 + quad) ^ (l15 & 7)) * 8)];

#pragma unroll
        for (int gs = 0; gs < 4; ++gs) {
            int grow = gs * 16 + l15;
            halfx8 bv0 = *(const halfx8*)&vsb[grow * 64 + (((0 + quad) ^ (grow & 7)) * 8)];
            halfx8 bv1 = *(const halfx8*)&vsb[grow * 64 + (((4 + quad) ^ (grow & 7)) * 8)];
            o[gs] = __builtin_amdgcn_mfma_f32_16x16x32_f16(ap0, bv0, o[gs], 0, 0, 0);
            o[gs] = __builtin_amdgcn_mfma_f32_16x16x32_f16(ap1, bv1, o[gs], 0, 0, 0);
        }
    }

    float l[4];
#pragma unroll
    for (int r = 0; r < 4; ++r) {
        float ss = l_lane[r];
#pragma unroll
        for (int off = 1; off < 16; off <<= 1)
            ss += __shfl_xor(ss, off, 64);
        l[r] = ss;
    }
#pragma unroll
    for (int gs = 0; gs < 4; ++gs) {
#pragma unroll
        for (int r = 0; r < 4; ++r) {
            int row = row0 + w * 16 + quad * 4 + r;
            out[row * 64 + gs * 16 + l15] = o[gs][r] / l[r];
        }
    }
}

// ---------------------------------------------------------------------------
extern "C" void kernel_launch(void* const* d_in, const int* in_sizes, int n_in,
                              void* d_out, int out_size, void* d_ws, size_t ws_size,
                              hipStream_t stream) {
    const float* x    = (const float*)d_in[0];
    const int*   vlen = (const int*)  d_in[1];
    const float* Wq   = (const float*)d_in[2];
    const float* bq   = (const float*)d_in[3];
    const float* Wk   = (const float*)d_in[4];
    const float* bk   = (const float*)d_in[5];
    const float* Wv   = (const float*)d_in[6];
    const float* bv   = (const float*)d_in[7];
    float* out = (float*)d_out;

    unsigned short* k_ws  = (unsigned short*)d_ws;
    unsigned short* vt_ws = k_ws + 32768 * 64;
    unsigned int*   flags = (unsigned int*)((char*)d_ws +
                              (size_t)2 * (32768 * 64 + 32 * 64 * 1024));

    hipMemsetAsync(flags, 0, 32 * 32 * sizeof(unsigned int), stream);
    fused_attn_kernel<<<512, 256, 0, stream>>>(
        x, Wq, bq, Wk, bk, Wv, bv, vlen, k_ws, vt_ws, flags, out);
}

// Round 14
// 105.598 us; speedup vs baseline: 1.9020x; 1.9020x over previous
//
#include <hip/hip_runtime.h>
#include <stdint.h>

// Problem constants: B=32, N=1024, C=64, G=64
//
// R14: single kernel, no workspace, no cross-block sync (R10/R13 proved any
// in-kernel spin sync costs ~100us on gfx950 due to cross-XCD non-coherence).
// Based on R12 (best: kernel ~40us) with the serialized chain collapsed:
//  - wave-private x staging: stage->frag-read is same-wave ds-ordered,
//    no barrier needed between them.
//  - Wk/Wv hi B-fragments live in REGISTERS (16 halfx8 = 64 VGPR), freeing
//    16KB LDS -> KL and VS fully double-buffered -> ONE barrier per tile;
//    produce(t+1) and consume(t) interleave between barriers.
//
// LDS (56 KB, shorts):
//   Q   [    0, 4096)  q tile (A-layout staged), wave-private rows
//   XHW [ 4096, 8192)  x_hi, wave-private 16-row slices (w*1024)
//   KL0 [ 8192,12288)  k tile buf0   (prologue: Wq_hi)
//   KL1 [12288,16384)  k tile buf1   (prologue: Wq_lo)
//   VS0 [16384,20480)  V^T buf0      (prologue: x_lo wave slices)
//   VS1 [20480,24576)  V^T buf1      (prologue: Wk_hi)
//   PS  [24576,28672)  P fp16, wave slices (prologue: Wv_hi)

typedef __attribute__((ext_vector_type(4))) float    floatx4;
typedef __attribute__((ext_vector_type(8))) _Float16 halfx8;

static __device__ __forceinline__ unsigned short f2h(float f) {
    union { _Float16 h; unsigned short u; } v; v.h = (_Float16)f;
    return v.u;
}
static __device__ __forceinline__ float h2f(unsigned short u) {
    union { unsigned short u; _Float16 h; } v; v.u = u;
    return (float)v.h;
}

#define MFMA16(a, bb, c) __builtin_amdgcn_mfma_f32_16x16x32_f16((a), (bb), (c), 0, 0, 0)

__global__ __launch_bounds__(256, 2) void fused_attn_kernel(
    const float* __restrict__ x,
    const float* __restrict__ Wq, const float* __restrict__ bq,
    const float* __restrict__ Wk, const float* __restrict__ bk,
    const float* __restrict__ Wv, const float* __restrict__ bv,
    const int* __restrict__ valid_len, float* __restrict__ out)
{
    __shared__ __align__(16) unsigned short smem[28672];   // 56 KB

    const int Q_OFF = 0, XH_OFF = 4096, KL0_OFF = 8192, KL1_OFF = 12288,
              VS0_OFF = 16384, VS1_OFF = 20480, PS_OFF = 24576;

    const int tid  = threadIdx.x;
    const int blk  = blockIdx.x;          // 0..511
    const int row0 = blk * 64;            // b*1024 + n0
    const int b    = blk >> 4;
    const int lane = tid & 63;
    const int w    = tid >> 6;
    const int l15  = lane & 15;
    const int quad = lane >> 4;

    const int xsl  = XH_OFF + w * 1024;   // wave-private x_hi slice
    // A-frag addresses within a 16-row wave slice (row = l15)
    const int fidx0 = l15 * 64 + (((0 + quad) ^ (l15 & 7)) * 8);
    const int fidx1 = l15 * 64 + (((4 + quad) ^ (l15 & 7)) * 8);
    // wave-private staging coords: lane -> row (lane>>2), chunks (lane&3), (lane&3)+4
    const int rl   = lane >> 2;
    const int c8a  = lane & 3;
    const int c8b  = (lane & 3) + 4;
    const int sidx_a = rl * 64 + ((c8a ^ (rl & 7)) * 8);
    const int sidx_b = rl * 64 + ((c8b ^ (rl & 7)) * 8);

    const int vl    = valid_len[b];
    const int nt    = (vl == 0) ? 16 : ((vl + 63) >> 6);   // vl==0 -> uniform softmax
    const int fullt = vl >> 6;

    // ========================= Prologue =========================
    // wave-private stage of q-rows x: hi -> XHW slice, lo -> VS0 slice
    {
        const float* xrow = x + (size_t)(row0 + w * 16) * 64;
#pragma unroll
        for (int i = 0; i < 2; ++i) {
            int c8 = (i == 0) ? c8a : c8b;
            int sidx = (i == 0) ? sidx_a : sidx_b;
            const float4* gp = (const float4*)(xrow + rl * 64 + c8 * 8);
            float4 f0 = gp[0], f1 = gp[1];
            float fv[8] = { f0.x, f0.y, f0.z, f0.w, f1.x, f1.y, f1.z, f1.w };
            __align__(16) unsigned short thi[8], tlo[8];
#pragma unroll
            for (int j = 0; j < 8; ++j) {
                unsigned short hi = f2h(fv[j]);
                thi[j] = hi;
                tlo[j] = f2h(fv[j] - h2f(hi));
            }
            *(uint4*)&smem[xsl + sidx]               = *(uint4*)thi;
            *(uint4*)&smem[VS0_OFF + w * 1024 + sidx] = *(uint4*)tlo;
        }
    }
    // cooperative W stages: Wq hi/lo -> KL0/KL1, Wk hi -> VS1, Wv hi -> PS
    {
        int g = tid & 63, ci = tid >> 6;
#pragma unroll
        for (int j = 0; j < 16; ++j) {
            int c = ci * 16 + j;
            int idx = g * 64 + (((c >> 3) ^ (g & 7)) * 8) + (c & 7);
            float fq = Wq[c * 64 + g];
            unsigned short qhi = f2h(fq);
            smem[KL0_OFF + idx] = qhi;
            smem[KL1_OFF + idx] = f2h(fq - h2f(qhi));
            smem[VS1_OFF + idx] = f2h(Wk[c * 64 + g]);
            smem[PS_OFF  + idx] = f2h(Wv[c * 64 + g]);
        }
    }
    __syncthreads();                      // P1

    // Wk/Wv hi B-fragments -> registers (resident)
    halfx8 wkf0[4], wkf1[4], wvf0[4], wvf1[4];
#pragma unroll
    for (int gs = 0; gs < 4; ++gs) {
        int brow = gs * 16 + l15;
        int b0 = brow * 64 + (((0 + quad) ^ (brow & 7)) * 8);
        int b1 = brow * 64 + (((4 + quad) ^ (brow & 7)) * 8);
        wkf0[gs] = *(const halfx8*)&smem[VS1_OFF + b0];
        wkf1[gs] = *(const halfx8*)&smem[VS1_OFF + b1];
        wvf0[gs] = *(const halfx8*)&smem[PS_OFF + b0];
        wvf1[gs] = *(const halfx8*)&smem[PS_OFF + b1];
    }

    // q projection (full split precision), write Q (own-wave rows)
    {
        halfx8 ah0 = *(const halfx8*)&smem[xsl + fidx0];
        halfx8 ah1 = *(const halfx8*)&smem[xsl + fidx1];
        halfx8 al0 = *(const halfx8*)&smem[VS0_OFF + w * 1024 + fidx0];
        halfx8 al1 = *(const halfx8*)&smem[VS0_OFF + w * 1024 + fidx1];
#pragma unroll
        for (int gs = 0; gs < 4; ++gs) {
            int brow = gs * 16 + l15;
            float bb = bq[gs * 16 + l15];
            floatx4 acc = { bb, bb, bb, bb };
            int b0 = brow * 64 + (((0 + quad) ^ (brow & 7)) * 8);
            int b1 = brow * 64 + (((4 + quad) ^ (brow & 7)) * 8);
            halfx8 bh0 = *(const halfx8*)&smem[KL0_OFF + b0];
            halfx8 bh1 = *(const halfx8*)&smem[KL0_OFF + b1];
            halfx8 bl0 = *(const halfx8*)&smem[KL1_OFF + b0];
            halfx8 bl1 = *(const halfx8*)&smem[KL1_OFF + b1];
            acc = MFMA16(ah0, bh0, acc);
            acc = MFMA16(ah1, bh1, acc);
            acc = MFMA16(ah0, bl0, acc);
            acc = MFMA16(ah1, bl1, acc);
            acc = MFMA16(al0, bh0, acc);
            acc = MFMA16(al1, bh1, acc);
            int c8 = gs * 2 + (l15 >> 3);
#pragma unroll
            for (int r = 0; r < 4; ++r) {
                int row = w * 16 + quad * 4 + r;   // own-wave rows
                smem[Q_OFF + row * 64 + ((c8 ^ (row & 7)) * 8) + (l15 & 7)] = f2h(acc[r]);
            }
        }
    }
    // aq frags (own-wave rows; same-wave ds ordering — proven pattern R11/R12)
    const int arow = w * 16 + l15;
    halfx8 aq0 = *(const halfx8*)&smem[Q_OFF + arow * 64 + (((0 + quad) ^ (arow & 7)) * 8)];
    halfx8 aq1 = *(const halfx8*)&smem[Q_OFF + arow * 64 + (((4 + quad) ^ (arow & 7)) * 8)];

    // stage x(key-tile 0) hi -> XHW (own-wave; frag reads above already done)
    {
        const float* xrow = x + (size_t)(b * 1024 + w * 16) * 64;
#pragma unroll
        for (int i = 0; i < 2; ++i) {
            int c8 = (i == 0) ? c8a : c8b;
            int sidx = (i == 0) ? sidx_a : sidx_b;
            const float4* gp = (const float4*)(xrow + rl * 64 + c8 * 8);
            float4 f0 = gp[0], f1 = gp[1];
            __align__(16) unsigned short thi[8] = {
                f2h(f0.x), f2h(f0.y), f2h(f0.z), f2h(f0.w),
                f2h(f1.x), f2h(f1.y), f2h(f1.z), f2h(f1.w) };
            *(uint4*)&smem[xsl + sidx] = *(uint4*)thi;
        }
    }
    __syncthreads();                      // P2: all W / x_lo reads done -> buffers free

    // produce K/V(0) into buf0 (hi-only, W frags from regs)
    {
        halfx8 kxh0 = *(const halfx8*)&smem[xsl + fidx0];
        halfx8 kxh1 = *(const halfx8*)&smem[xsl + fidx1];
#pragma unroll
        for (int gs = 0; gs < 4; ++gs) {
            float bbk = bk[gs * 16 + l15];
            float bbv = bv[gs * 16 + l15];
            floatx4 kacc = { bbk, bbk, bbk, bbk };
            floatx4 vacc = { bbv, bbv, bbv, bbv };
            kacc = MFMA16(kxh0, wkf0[gs], kacc);
            kacc = MFMA16(kxh1, wkf1[gs], kacc);
            vacc = MFMA16(kxh0, wvf0[gs], vacc);
            vacc = MFMA16(kxh1, wvf1[gs], vacc);
            int c8 = gs * 2 + (l15 >> 3);
            int g  = gs * 16 + l15;
#pragma unroll
            for (int r = 0; r < 4; ++r) {
                int key = w * 16 + quad * 4 + r;
                smem[KL0_OFF + key * 64 + ((c8 ^ (key & 7)) * 8) + (l15 & 7)] = f2h(kacc[r]);
                smem[VS0_OFF + g * 64 + (((key >> 3) ^ (g & 7)) * 8) + (key & 7)] = f2h(vacc[r]);
            }
        }
    }

    float m_r[4]    = { -INFINITY, -INFINITY, -INFINITY, -INFINITY };
    float l_lane[4] = { 0.f, 0.f, 0.f, 0.f };
    floatx4 o[4] = { {0,0,0,0}, {0,0,0,0}, {0,0,0,0}, {0,0,0,0} };

    // ==================== K-tile loop: ONE barrier per tile ====================
    for (int t = 0; t < nt; ++t) {
        bool pre = (t + 1) < nt;
        float4 pfa0, pfa1, pfb0, pfb1;
        if (pre) {
            const float* xrow = x + (size_t)(b * 1024 + (t + 1) * 64 + w * 16) * 64;
            pfa0 = ((const float4*)(xrow + rl * 64 + c8a * 8))[0];
            pfa1 = ((const float4*)(xrow + rl * 64 + c8a * 8))[1];
            pfb0 = ((const float4*)(xrow + rl * 64 + c8b * 8))[0];
            pfb1 = ((const float4*)(xrow + rl * 64 + c8b * 8))[1];
        }
        __syncthreads();   // KL/VS(t) visible; consume(t-1) reads of (t+1)-parity done

        // ---- produce tile t+1 into parity (t+1)&1 ----
        if (pre) {
            __align__(16) unsigned short ta[8] = {
                f2h(pfa0.x), f2h(pfa0.y), f2h(pfa0.z), f2h(pfa0.w),
                f2h(pfa1.x), f2h(pfa1.y), f2h(pfa1.z), f2h(pfa1.w) };
            __align__(16) unsigned short tb[8] = {
                f2h(pfb0.x), f2h(pfb0.y), f2h(pfb0.z), f2h(pfb0.w),
                f2h(pfb1.x), f2h(pfb1.y), f2h(pfb1.z), f2h(pfb1.w) };
            *(uint4*)&smem[xsl + sidx_a] = *(uint4*)ta;
            *(uint4*)&smem[xsl + sidx_b] = *(uint4*)tb;
            halfx8 kxh0 = *(const halfx8*)&smem[xsl + fidx0];
            halfx8 kxh1 = *(const halfx8*)&smem[xsl + fidx1];
            const int KLn = ((t + 1) & 1) ? KL1_OFF : KL0_OFF;
            const int VSn = ((t + 1) & 1) ? VS1_OFF : VS0_OFF;
#pragma unroll
            for (int gs = 0; gs < 4; ++gs) {
                float bbk = bk[gs * 16 + l15];
                float bbv = bv[gs * 16 + l15];
                floatx4 kacc = { bbk, bbk, bbk, bbk };
                floatx4 vacc = { bbv, bbv, bbv, bbv };
                kacc = MFMA16(kxh0, wkf0[gs], kacc);
                kacc = MFMA16(kxh1, wkf1[gs], kacc);
                vacc = MFMA16(kxh0, wvf0[gs], vacc);
                vacc = MFMA16(kxh1, wvf1[gs], vacc);
                int c8 = gs * 2 + (l15 >> 3);
                int g  = gs * 16 + l15;
#pragma unroll
                for (int r = 0; r < 4; ++r) {
                    int key = w * 16 + quad * 4 + r;
                    smem[KLn + key * 64 + ((c8 ^ (key & 7)) * 8) + (l15 & 7)] = f2h(kacc[r]);
                    smem[VSn + g * 64 + (((key >> 3) ^ (g & 7)) * 8) + (key & 7)] = f2h(vacc[r]);
                }
            }
        }

        // ---- consume tile t from parity t&1 ----
        const int KLc = (t & 1) ? KL1_OFF : KL0_OFF;
        const int VSc = (t & 1) ? VS1_OFF : VS0_OFF;

        floatx4 s[4];
#pragma unroll
        for (int sub = 0; sub < 4; ++sub) {
            int krow = sub * 16 + l15;
            halfx8 bk0 = *(const halfx8*)&smem[KLc + krow * 64 + (((0 + quad) ^ (krow & 7)) * 8)];
            halfx8 bk1 = *(const halfx8*)&smem[KLc + krow * 64 + (((4 + quad) ^ (krow & 7)) * 8)];
            floatx4 acc = { 0, 0, 0, 0 };
            acc = MFMA16(aq0, bk0, acc);
            acc = MFMA16(aq1, bk1, acc);
            s[sub] = acc;
        }
        if (t >= fullt) {
#pragma unroll
            for (int sub = 0; sub < 4; ++sub) {
                int key = t * 64 + sub * 16 + l15;
                if (key >= vl) { s[sub][0] = -1e6f; s[sub][1] = -1e6f; s[sub][2] = -1e6f; s[sub][3] = -1e6f; }
            }
        }

        // online softmax: wave-consistent max; per-lane deferred sum
        float p[4][4];
        float alpha[4];
#pragma unroll
        for (int r = 0; r < 4; ++r) {
            float mx = fmaxf(fmaxf(s[0][r], s[1][r]), fmaxf(s[2][r], s[3][r]));
#pragma unroll
            for (int off = 1; off < 16; off <<= 1)
                mx = fmaxf(mx, __shfl_xor(mx, off, 64));
            float mnew = fmaxf(m_r[r], mx);
            alpha[r] = __expf(m_r[r] - mnew);
            float psum = 0.f;
#pragma unroll
            for (int sub = 0; sub < 4; ++sub) {
                float pv = __expf(s[sub][r] - mnew);
                p[sub][r] = pv;
                psum += pv;
            }
            l_lane[r] = l_lane[r] * alpha[r] + psum;
            m_r[r] = mnew;
        }
#pragma unroll
        for (int gs = 0; gs < 4; ++gs) {
            o[gs][0] *= alpha[0]; o[gs][1] *= alpha[1];
            o[gs][2] *= alpha[2]; o[gs][3] *= alpha[3];
        }

        // P (D-layout) -> fp16 LDS (A-layout, wave slice of PS)
        unsigned short* psw = &smem[PS_OFF + w * 1024];
#pragma unroll
        for (int sub = 0; sub < 4; ++sub) {
            int c8 = sub * 2 + (l15 >> 3);
#pragma unroll
            for (int r = 0; r < 4; ++r) {
                int row = quad * 4 + r;
                psw[row * 64 + ((c8 ^ (row & 7)) * 8) + (l15 & 7)] = f2h(p[sub][r]);
            }
        }
        halfx8 ap0 = *(const halfx8*)&psw[fidx0];
        halfx8 ap1 = *(const halfx8*)&psw[fidx1];

#pragma unroll
        for (int gs = 0; gs < 4; ++gs) {
            int grow = gs * 16 + l15;
            halfx8 bv0 = *(const halfx8*)&smem[VSc + grow * 64 + (((0 + quad) ^ (grow & 7)) * 8)];
            halfx8 bv1 = *(const halfx8*)&smem[VSc + grow * 64 + (((4 + quad) ^ (grow & 7)) * 8)];
            o[gs] = MFMA16(ap0, bv0, o[gs]);
            o[gs] = MFMA16(ap1, bv1, o[gs]);
        }
    }

    // ---- final 16-lane sum butterfly, store ----
    float l[4];
#pragma unroll
    for (int r = 0; r < 4; ++r) {
        float ss = l_lane[r];
#pragma unroll
        for (int off = 1; off < 16; off <<= 1)
            ss += __shfl_xor(ss, off, 64);
        l[r] = ss;
    }
#pragma unroll
    for (int gs = 0; gs < 4; ++gs) {
#pragma unroll
        for (int r = 0; r < 4; ++r) {
            int row = row0 + w * 16 + quad * 4 + r;
            out[row * 64 + gs * 16 + l15] = o[gs][r] / l[r];
        }
    }
}

// ---------------------------------------------------------------------------
extern "C" void kernel_launch(void* const* d_in, const int* in_sizes, int n_in,
                              void* d_out, int out_size, void* d_ws, size_t ws_size,
                              hipStream_t stream) {
    const float* x    = (const float*)d_in[0];
    const int*   vlen = (const int*)  d_in[1];
    const float* Wq   = (const float*)d_in[2];
    const float* bq   = (const float*)d_in[3];
    const float* Wk   = (const float*)d_in[4];
    const float* bk   = (const float*)d_in[5];
    const float* Wv   = (const float*)d_in[6];
    const float* bv   = (const float*)d_in[7];
    float* out = (float*)d_out;

    fused_attn_kernel<<<512, 256, 0, stream>>>(
        x, Wq, bq, Wk, bk, Wv, bv, vlen, out);
}

// Round 15
// 105.472 us; speedup vs baseline: 1.9042x; 1.0012x over previous
//
#include <hip/hip_runtime.h>
#include <stdint.h>

// Problem constants: B=32, N=1024, C=64, G=64
//
// R15 = R14 + (1) device-side balanced job scheduling, (2) staging bank fix.
// R14 counters: kernel 41.4us, Occupancy 11.9% vs 25% structural -> load
// imbalance tail (all 16 blocks of a batch share nt=ceil(vl/64); CUs with two
// nt=16 blocks set the kernel duration). Every block computes an identical
// rank-sort of the 32 batches by nt and takes job:
//   blk<256:  batch = rank[blk>>4]          (heavy half)
//   blk>=256: batch = rank[31-((blk-256)>>4)] (light half, reversed)
// Under (i,i+256) CU co-location this pairs heavy+light (pair sum ~const);
// under any dispatch model it decorrelates same-batch CU pairs.
// Bank fix: wave-private staging chunks 2*(lane&3), 2*(lane&3)+1 (R14 used
// lane&3, (lane&3)+4 -> XOR swizzle collapsed onto banks 0-15, 1.25M conflicts).

typedef __attribute__((ext_vector_type(4))) float    floatx4;
typedef __attribute__((ext_vector_type(8))) _Float16 halfx8;

static __device__ __forceinline__ unsigned short f2h(float f) {
    union { _Float16 h; unsigned short u; } v; v.h = (_Float16)f;
    return v.u;
}
static __device__ __forceinline__ float h2f(unsigned short u) {
    union { unsigned short u; _Float16 h; } v; v.u = u;
    return (float)v.h;
}

#define MFMA16(a, bb, c) __builtin_amdgcn_mfma_f32_16x16x32_f16((a), (bb), (c), 0, 0, 0)

__global__ __launch_bounds__(256, 2) void fused_attn_kernel(
    const float* __restrict__ x,
    const float* __restrict__ Wq, const float* __restrict__ bq,
    const float* __restrict__ Wk, const float* __restrict__ bk,
    const float* __restrict__ Wv, const float* __restrict__ bv,
    const int* __restrict__ valid_len, float* __restrict__ out)
{
    __shared__ __align__(16) unsigned short smem[28672];   // 56 KB
    __shared__ int sched[32];

    const int Q_OFF = 0, XH_OFF = 4096, KL0_OFF = 8192, KL1_OFF = 12288,
              VS0_OFF = 16384, VS1_OFF = 20480, PS_OFF = 24576;

    const int tid  = threadIdx.x;
    const int blk  = blockIdx.x;          // 0..511
    const int lane = tid & 63;
    const int w    = tid >> 6;
    const int l15  = lane & 15;
    const int quad = lane >> 4;

    // ---------- device-side balanced schedule (identical in every block) ----
    if (tid < 32) {
        int vlb = valid_len[tid];
        int ntb = (vlb == 0) ? 16 : ((vlb + 63) >> 6);
        int rank = 0;
        for (int b2 = 0; b2 < 32; ++b2) {
            int vl2 = valid_len[b2];
            int nt2 = (vl2 == 0) ? 16 : ((vl2 + 63) >> 6);
            rank += (nt2 > ntb) || (nt2 == ntb && b2 < tid);
        }
        sched[rank] = tid;
    }
    __syncthreads();

    const int hv   = (blk < 256);
    const int b    = hv ? sched[blk >> 4] : sched[31 - ((blk - 256) >> 4)];
    const int n0   = (blk & 15) * 64;     // (blk-256)&15 == blk&15
    const int row0 = b * 1024 + n0;

    const int xsl  = XH_OFF + w * 1024;   // wave-private x_hi slice
    const int fidx0 = l15 * 64 + (((0 + quad) ^ (l15 & 7)) * 8);
    const int fidx1 = l15 * 64 + (((4 + quad) ^ (l15 & 7)) * 8);
    // wave-private staging: lane -> row lane>>2, chunks 2*(lane&3), 2*(lane&3)+1
    const int rl   = lane >> 2;
    const int c8a  = 2 * (lane & 3);
    const int c8b  = 2 * (lane & 3) + 1;
    const int sidx_a = rl * 64 + ((c8a ^ (rl & 7)) * 8);
    const int sidx_b = rl * 64 + ((c8b ^ (rl & 7)) * 8);

    const int vl    = valid_len[b];
    const int nt    = (vl == 0) ? 16 : ((vl + 63) >> 6);
    const int fullt = vl >> 6;

    // ========================= Prologue =========================
    {
        const float* xrow = x + (size_t)(row0 + w * 16) * 64;
#pragma unroll
        for (int i = 0; i < 2; ++i) {
            int c8 = (i == 0) ? c8a : c8b;
            int sidx = (i == 0) ? sidx_a : sidx_b;
            const float4* gp = (const float4*)(xrow + rl * 64 + c8 * 8);
            float4 f0 = gp[0], f1 = gp[1];
            float fv[8] = { f0.x, f0.y, f0.z, f0.w, f1.x, f1.y, f1.z, f1.w };
            __align__(16) unsigned short thi[8], tlo[8];
#pragma unroll
            for (int j = 0; j < 8; ++j) {
                unsigned short hi = f2h(fv[j]);
                thi[j] = hi;
                tlo[j] = f2h(fv[j] - h2f(hi));
            }
            *(uint4*)&smem[xsl + sidx]                = *(uint4*)thi;
            *(uint4*)&smem[VS0_OFF + w * 1024 + sidx] = *(uint4*)tlo;
        }
    }
    {
        int g = tid & 63, ci = tid >> 6;
#pragma unroll
        for (int j = 0; j < 16; ++j) {
            int c = ci * 16 + j;
            int idx = g * 64 + (((c >> 3) ^ (g & 7)) * 8) + (c & 7);
            float fq = Wq[c * 64 + g];
            unsigned short qhi = f2h(fq);
            smem[KL0_OFF + idx] = qhi;
            smem[KL1_OFF + idx] = f2h(fq - h2f(qhi));
            smem[VS1_OFF + idx] = f2h(Wk[c * 64 + g]);
            smem[PS_OFF  + idx] = f2h(Wv[c * 64 + g]);
        }
    }
    __syncthreads();                      // P1

    halfx8 wkf0[4], wkf1[4], wvf0[4], wvf1[4];
#pragma unroll
    for (int gs = 0; gs < 4; ++gs) {
        int brow = gs * 16 + l15;
        int b0 = brow * 64 + (((0 + quad) ^ (brow & 7)) * 8);
        int b1 = brow * 64 + (((4 + quad) ^ (brow & 7)) * 8);
        wkf0[gs] = *(const halfx8*)&smem[VS1_OFF + b0];
        wkf1[gs] = *(const halfx8*)&smem[VS1_OFF + b1];
        wvf0[gs] = *(const halfx8*)&smem[PS_OFF + b0];
        wvf1[gs] = *(const halfx8*)&smem[PS_OFF + b1];
    }

    // q projection (full split precision), write Q (own-wave rows)
    {
        halfx8 ah0 = *(const halfx8*)&smem[xsl + fidx0];
        halfx8 ah1 = *(const halfx8*)&smem[xsl + fidx1];
        halfx8 al0 = *(const halfx8*)&smem[VS0_OFF + w * 1024 + fidx0];
        halfx8 al1 = *(const halfx8*)&smem[VS0_OFF + w * 1024 + fidx1];
#pragma unroll
        for (int gs = 0; gs < 4; ++gs) {
            int brow = gs * 16 + l15;
            float bb = bq[gs * 16 + l15];
            floatx4 acc = { bb, bb, bb, bb };
            int b0 = brow * 64 + (((0 + quad) ^ (brow & 7)) * 8);
            int b1 = brow * 64 + (((4 + quad) ^ (brow & 7)) * 8);
            halfx8 bh0 = *(const halfx8*)&smem[KL0_OFF + b0];
            halfx8 bh1 = *(const halfx8*)&smem[KL0_OFF + b1];
            halfx8 bl0 = *(const halfx8*)&smem[KL1_OFF + b0];
            halfx8 bl1 = *(const halfx8*)&smem[KL1_OFF + b1];
            acc = MFMA16(ah0, bh0, acc);
            acc = MFMA16(ah1, bh1, acc);
            acc = MFMA16(ah0, bl0, acc);
            acc = MFMA16(ah1, bl1, acc);
            acc = MFMA16(al0, bh0, acc);
            acc = MFMA16(al1, bh1, acc);
            int c8 = gs * 2 + (l15 >> 3);
#pragma unroll
            for (int r = 0; r < 4; ++r) {
                int row = w * 16 + quad * 4 + r;   // own-wave rows
                smem[Q_OFF + row * 64 + ((c8 ^ (row & 7)) * 8) + (l15 & 7)] = f2h(acc[r]);
            }
        }
    }
    const int arow = w * 16 + l15;
    halfx8 aq0 = *(const halfx8*)&smem[Q_OFF + arow * 64 + (((0 + quad) ^ (arow & 7)) * 8)];
    halfx8 aq1 = *(const halfx8*)&smem[Q_OFF + arow * 64 + (((4 + quad) ^ (arow & 7)) * 8)];

    // stage x(key-tile 0) hi -> XHW (own-wave; frag reads above already done)
    {
        const float* xrow = x + (size_t)(b * 1024 + w * 16) * 64;
#pragma unroll
        for (int i = 0; i < 2; ++i) {
            int c8 = (i == 0) ? c8a : c8b;
            int sidx = (i == 0) ? sidx_a : sidx_b;
            const float4* gp = (const float4*)(xrow + rl * 64 + c8 * 8);
            float4 f0 = gp[0], f1 = gp[1];
            __align__(16) unsigned short thi[8] = {
                f2h(f0.x), f2h(f0.y), f2h(f0.z), f2h(f0.w),
                f2h(f1.x), f2h(f1.y), f2h(f1.z), f2h(f1.w) };
            *(uint4*)&smem[xsl + sidx] = *(uint4*)thi;
        }
    }
    __syncthreads();                      // P2

    // produce K/V(0) into buf0 (hi-only, W frags from regs)
    {
        halfx8 kxh0 = *(const halfx8*)&smem[xsl + fidx0];
        halfx8 kxh1 = *(const halfx8*)&smem[xsl + fidx1];
#pragma unroll
        for (int gs = 0; gs < 4; ++gs) {
            float bbk = bk[gs * 16 + l15];
            float bbv = bv[gs * 16 + l15];
            floatx4 kacc = { bbk, bbk, bbk, bbk };
            floatx4 vacc = { bbv, bbv, bbv, bbv };
            kacc = MFMA16(kxh0, wkf0[gs], kacc);
            kacc = MFMA16(kxh1, wkf1[gs], kacc);
            vacc = MFMA16(kxh0, wvf0[gs], vacc);
            vacc = MFMA16(kxh1, wvf1[gs], vacc);
            int c8 = gs * 2 + (l15 >> 3);
            int g  = gs * 16 + l15;
#pragma unroll
            for (int r = 0; r < 4; ++r) {
                int key = w * 16 + quad * 4 + r;
                smem[KL0_OFF + key * 64 + ((c8 ^ (key & 7)) * 8) + (l15 & 7)] = f2h(kacc[r]);
                smem[VS0_OFF + g * 64 + (((key >> 3) ^ (g & 7)) * 8) + (key & 7)] = f2h(vacc[r]);
            }
        }
    }

    float m_r[4]    = { -INFINITY, -INFINITY, -INFINITY, -INFINITY };
    float l_lane[4] = { 0.f, 0.f, 0.f, 0.f };
    floatx4 o[4] = { {0,0,0,0}, {0,0,0,0}, {0,0,0,0}, {0,0,0,0} };

    // ==================== K-tile loop: ONE barrier per tile ====================
    for (int t = 0; t < nt; ++t) {
        bool pre = (t + 1) < nt;
        float4 pfa0, pfa1, pfb0, pfb1;
        if (pre) {
            const float* xrow = x + (size_t)(b * 1024 + (t + 1) * 64 + w * 16) * 64;
            pfa0 = ((const float4*)(xrow + rl * 64 + c8a * 8))[0];
            pfa1 = ((const float4*)(xrow + rl * 64 + c8a * 8))[1];
            pfb0 = ((const float4*)(xrow + rl * 64 + c8b * 8))[0];
            pfb1 = ((const float4*)(xrow + rl * 64 + c8b * 8))[1];
        }
        __syncthreads();   // KL/VS(t) visible; prior reads of (t+1)-parity done

        // ---- produce tile t+1 into parity (t+1)&1 ----
        if (pre) {
            __align__(16) unsigned short ta[8] = {
                f2h(pfa0.x), f2h(pfa0.y), f2h(pfa0.z), f2h(pfa0.w),
                f2h(pfa1.x), f2h(pfa1.y), f2h(pfa1.z), f2h(pfa1.w) };
            __align__(16) unsigned short tb[8] = {
                f2h(pfb0.x), f2h(pfb0.y), f2h(pfb0.z), f2h(pfb0.w),
                f2h(pfb1.x), f2h(pfb1.y), f2h(pfb1.z), f2h(pfb1.w) };
            *(uint4*)&smem[xsl + sidx_a] = *(uint4*)ta;
            *(uint4*)&smem[xsl + sidx_b] = *(uint4*)tb;
            halfx8 kxh0 = *(const halfx8*)&smem[xsl + fidx0];
            halfx8 kxh1 = *(const halfx8*)&smem[xsl + fidx1];
            const int KLn = ((t + 1) & 1) ? KL1_OFF : KL0_OFF;
            const int VSn = ((t + 1) & 1) ? VS1_OFF : VS0_OFF;
#pragma unroll
            for (int gs = 0; gs < 4; ++gs) {
                float bbk = bk[gs * 16 + l15];
                float bbv = bv[gs * 16 + l15];
                floatx4 kacc = { bbk, bbk, bbk, bbk };
                floatx4 vacc = { bbv, bbv, bbv, bbv };
                kacc = MFMA16(kxh0, wkf0[gs], kacc);
                kacc = MFMA16(kxh1, wkf1[gs], kacc);
                vacc = MFMA16(kxh0, wvf0[gs], vacc);
                vacc = MFMA16(kxh1, wvf1[gs], vacc);
                int c8 = gs * 2 + (l15 >> 3);
                int g  = gs * 16 + l15;
#pragma unroll
                for (int r = 0; r < 4; ++r) {
                    int key = w * 16 + quad * 4 + r;
                    smem[KLn + key * 64 + ((c8 ^ (key & 7)) * 8) + (l15 & 7)] = f2h(kacc[r]);
                    smem[VSn + g * 64 + (((key >> 3) ^ (g & 7)) * 8) + (key & 7)] = f2h(vacc[r]);
                }
            }
        }

        // ---- consume tile t from parity t&1 ----
        const int KLc = (t & 1) ? KL1_OFF : KL0_OFF;
        const int VSc = (t & 1) ? VS1_OFF : VS0_OFF;

        floatx4 s[4];
#pragma unroll
        for (int sub = 0; sub < 4; ++sub) {
            int krow = sub * 16 + l15;
            halfx8 bk0 = *(const halfx8*)&smem[KLc + krow * 64 + (((0 + quad) ^ (krow & 7)) * 8)];
            halfx8 bk1 = *(const halfx8*)&smem[KLc + krow * 64 + (((4 + quad) ^ (krow & 7)) * 8)];
            floatx4 acc = { 0, 0, 0, 0 };
            acc = MFMA16(aq0, bk0, acc);
            acc = MFMA16(aq1, bk1, acc);
            s[sub] = acc;
        }
        if (t >= fullt) {
#pragma unroll
            for (int sub = 0; sub < 4; ++sub) {
                int key = t * 64 + sub * 16 + l15;
                if (key >= vl) { s[sub][0] = -1e6f; s[sub][1] = -1e6f; s[sub][2] = -1e6f; s[sub][3] = -1e6f; }
            }
        }

        float p[4][4];
        float alpha[4];
#pragma unroll
        for (int r = 0; r < 4; ++r) {
            float mx = fmaxf(fmaxf(s[0][r], s[1][r]), fmaxf(s[2][r], s[3][r]));
#pragma unroll
            for (int off = 1; off < 16; off <<= 1)
                mx = fmaxf(mx, __shfl_xor(mx, off, 64));
            float mnew = fmaxf(m_r[r], mx);
            alpha[r] = __expf(m_r[r] - mnew);
            float psum = 0.f;
#pragma unroll
            for (int sub = 0; sub < 4; ++sub) {
                float pv = __expf(s[sub][r] - mnew);
                p[sub][r] = pv;
                psum += pv;
            }
            l_lane[r] = l_lane[r] * alpha[r] + psum;
            m_r[r] = mnew;
        }
#pragma unroll
        for (int gs = 0; gs < 4; ++gs) {
            o[gs][0] *= alpha[0]; o[gs][1] *= alpha[1];
            o[gs][2] *= alpha[2]; o[gs][3] *= alpha[3];
        }

        unsigned short* psw = &smem[PS_OFF + w * 1024];
#pragma unroll
        for (int sub = 0; sub < 4; ++sub) {
            int c8 = sub * 2 + (l15 >> 3);
#pragma unroll
            for (int r = 0; r < 4; ++r) {
                int row = quad * 4 + r;
                psw[row * 64 + ((c8 ^ (row & 7)) * 8) + (l15 & 7)] = f2h(p[sub][r]);
            }
        }
        halfx8 ap0 = *(const halfx8*)&psw[fidx0];
        halfx8 ap1 = *(const halfx8*)&psw[fidx1];

#pragma unroll
        for (int gs = 0; gs < 4; ++gs) {
            int grow = gs * 16 + l15;
            halfx8 bv0 = *(const halfx8*)&smem[VSc + grow * 64 + (((0 + quad) ^ (grow & 7)) * 8)];
            halfx8 bv1 = *(const halfx8*)&smem[VSc + grow * 64 + (((4 + quad) ^ (grow & 7)) * 8)];
            o[gs] = MFMA16(ap0, bv0, o[gs]);
            o[gs] = MFMA16(ap1, bv1, o[gs]);
        }
    }

    // ---- final 16-lane sum butterfly, store ----
    float l[4];
#pragma unroll
    for (int r = 0; r < 4; ++r) {
        float ss = l_lane[r];
#pragma unroll
        for (int off = 1; off < 16; off <<= 1)
            ss += __shfl_xor(ss, off, 64);
        l[r] = ss;
    }
#pragma unroll
    for (int gs = 0; gs < 4; ++gs) {
#pragma unroll
        for (int r = 0; r < 4; ++r) {
            int row = row0 + w * 16 + quad * 4 + r;
            out[row * 64 + gs * 16 + l15] = o[gs][r] / l[r];
        }
    }
}

// ---------------------------------------------------------------------------
extern "C" void kernel_launch(void* const* d_in, const int* in_sizes, int n_in,
                              void* d_out, int out_size, void* d_ws, size_t ws_size,
                              hipStream_t stream) {
    const float* x    = (const float*)d_in[0];
    const int*   vlen = (const int*)  d_in[1];
    const float* Wq   = (const float*)d_in[2];
    const float* bq   = (const float*)d_in[3];
    const float* Wk   = (const float*)d_in[4];
    const float* bk   = (const float*)d_in[5];
    const float* Wv   = (const float*)d_in[6];
    const float* bv   = (const float*)d_in[7];
    float* out = (float*)d_out;

    fused_attn_kernel<<<512, 256, 0, stream>>>(
        x, Wq, bq, Wk, bk, Wv, bv, vlen, out);
}